// Round 1
// baseline (658.702 us; speedup 1.0000x reference)
//
#include <hip/hip_runtime.h>

#define B_  1024
#define C_  1024
#define HW_ 196
#define A_  8
#define CH_ 256
#define N1_ 2048   // A*CH
#define K2_ 2048   // A*CH

typedef __attribute__((ext_vector_type(8))) short short8;
typedef __attribute__((ext_vector_type(4))) float f32x4;

static __device__ __forceinline__ unsigned short f2bf(float x) {
  union { float f; unsigned u; } v; v.f = x;
  unsigned r = (v.u + 0x7FFFu + ((v.u >> 16) & 1u)) >> 16;  // RNE
  return (unsigned short)r;
}

// ---------------- 1. global average pool: one wave per (b,c) row ----------------
__global__ void pool_k(const float* __restrict__ f, float* __restrict__ pooled,
                       unsigned short* __restrict__ pooledb) {
  unsigned gid = blockIdx.x * blockDim.x + threadIdx.x;
  unsigned row = gid >> 6;
  int lane = threadIdx.x & 63;
  if (row >= (unsigned)(B_ * C_)) return;
  const float* p = f + (size_t)row * HW_;
  float s = p[lane] + p[lane + 64] + p[lane + 128];
  if (lane < 4) s += p[192 + lane];
  #pragma unroll
  for (int off = 32; off > 0; off >>= 1) s += __shfl_down(s, off, 64);
  if (lane == 0) {
    float m = s * (1.0f / 196.0f);
    pooled[row] = m;
    pooledb[row] = f2bf(m);
  }
}

// ---------------- 2. softmax gate over experts: one block per b ----------------
__global__ void gate_k(const float* __restrict__ pooled, const float* __restrict__ fc_w,
                       const float* __restrict__ fc_b, float* __restrict__ gate) {
  __shared__ float dots[A_];
  int b = blockIdx.x;
  int wave = threadIdx.x >> 6, lane = threadIdx.x & 63;
  const float* p = pooled + (size_t)b * C_;
  for (int e = wave; e < A_; e += 4) {
    const float* wrow = fc_w + (size_t)e * C_;
    float sum = 0.f;
    for (int c = lane; c < C_; c += 64) sum += p[c] * wrow[c];
    #pragma unroll
    for (int off = 32; off > 0; off >>= 1) sum += __shfl_down(sum, off, 64);
    if (lane == 0) dots[e] = sum + fc_b[e];
  }
  __syncthreads();
  if (threadIdx.x == 0) {
    float mx = dots[0];
    for (int e = 1; e < A_; ++e) mx = fmaxf(mx, dots[e]);
    float ex[A_], se = 0.f;
    for (int e = 0; e < A_; ++e) { ex[e] = __expf(dots[e] - mx); se += ex[e]; }
    float inv = 1.0f / se;
    for (int e = 0; e < A_; ++e) gate[(size_t)b * A_ + e] = ex[e] * inv;
  }
}

// ------- 3. transpose + fp32->bf16 convert: out[z][c][r] = in[z][r][c] -------
__global__ void tconv_k(const float* __restrict__ in0, unsigned short* __restrict__ out0,
                        int Cc, int inZ, int outZ, int OS) {
  __shared__ float tile[32][33];
  const float* in = in0 + (size_t)blockIdx.z * inZ;
  unsigned short* out = out0 + (size_t)blockIdx.z * outZ;
  int c0 = blockIdx.x * 32, r0 = blockIdx.y * 32;
  int tx = threadIdx.x & 31, ty = threadIdx.x >> 5;   // 32x8 threads
  #pragma unroll
  for (int i = 0; i < 32; i += 8)
    tile[ty + i][tx] = in[(size_t)(r0 + ty + i) * Cc + c0 + tx];
  __syncthreads();
  #pragma unroll
  for (int i = 0; i < 32; i += 8)
    out[(size_t)(c0 + ty + i) * OS + r0 + tx] = f2bf(tile[tx][ty + i]);
}

// ---------------- 4. GEMM1: gh[b,n] = relu(pooled.fc1_w + b1) * gate ----------------
// A = pooledb [1024][1024] bf16 row-major; Bt = w1t [2048][1024] bf16 (n-major, k-contig)
__global__ __launch_bounds__(256) void gemm1_k(const unsigned short* __restrict__ Ab,
                                               const unsigned short* __restrict__ Bt,
                                               const float* __restrict__ fc1_b,
                                               const float* __restrict__ gate,
                                               unsigned short* __restrict__ gh) {
  int w = threadIdx.x >> 6, lane = threadIdx.x & 63;
  int r = lane & 15, kg = lane >> 4;
  int brow = blockIdx.x * 64 + (w >> 1) * 32;
  int bcol = blockIdx.y * 64 + (w & 1) * 32;
  const short8* Ap0 = (const short8*)(Ab + (size_t)(brow + r) * C_ + kg * 8);
  const short8* Ap1 = (const short8*)(Ab + (size_t)(brow + 16 + r) * C_ + kg * 8);
  const short8* Bp0 = (const short8*)(Bt + (size_t)(bcol + r) * C_ + kg * 8);
  const short8* Bp1 = (const short8*)(Bt + (size_t)(bcol + 16 + r) * C_ + kg * 8);
  f32x4 acc[2][2];
  acc[0][0] = (f32x4){0,0,0,0}; acc[0][1] = acc[0][0];
  acc[1][0] = acc[0][0];        acc[1][1] = acc[0][0];
  #pragma unroll 4
  for (int k = 0; k < C_ / 32; ++k) {    // short8 index step 4 == 32 elems
    short8 a0 = Ap0[4 * k], a1 = Ap1[4 * k];
    short8 b0 = Bp0[4 * k], b1 = Bp1[4 * k];
    acc[0][0] = __builtin_amdgcn_mfma_f32_16x16x32_bf16(a0, b0, acc[0][0], 0, 0, 0);
    acc[0][1] = __builtin_amdgcn_mfma_f32_16x16x32_bf16(a0, b1, acc[0][1], 0, 0, 0);
    acc[1][0] = __builtin_amdgcn_mfma_f32_16x16x32_bf16(a1, b0, acc[1][0], 0, 0, 0);
    acc[1][1] = __builtin_amdgcn_mfma_f32_16x16x32_bf16(a1, b1, acc[1][1], 0, 0, 0);
  }
  #pragma unroll
  for (int mi = 0; mi < 2; ++mi)
    #pragma unroll
    for (int ni = 0; ni < 2; ++ni) {
      int col = bcol + ni * 16 + r;
      int aidx = col >> 8;
      float bias = fc1_b[col];
      #pragma unroll
      for (int reg = 0; reg < 4; ++reg) {
        int row = brow + mi * 16 + kg * 4 + reg;
        float val = acc[mi][ni][reg] + bias;
        val = fmaxf(val, 0.f) * gate[row * A_ + aidx];
        gh[(size_t)row * N1_ + col] = f2bf(val);
      }
    }
}

// ---------------- 5. GEMM2: mixed[b,c] = gh.fc2_w + gate.fc2_b ; s = 1+sigmoid ----------------
// A = gh [1024][2048] bf16; Bt = w2t [1024][2048] bf16 (c-major, k contiguous)
__global__ __launch_bounds__(256) void gemm2_k(const unsigned short* __restrict__ Ab,
                                               const unsigned short* __restrict__ Bt,
                                               const float* __restrict__ gate,
                                               const float* __restrict__ fc2_b,
                                               float* __restrict__ s_out) {
  int w = threadIdx.x >> 6, lane = threadIdx.x & 63;
  int r = lane & 15, kg = lane >> 4;
  int brow = blockIdx.x * 64 + (w >> 1) * 32;
  int bcol = blockIdx.y * 64 + (w & 1) * 32;
  const short8* Ap0 = (const short8*)(Ab + (size_t)(brow + r) * K2_ + kg * 8);
  const short8* Ap1 = (const short8*)(Ab + (size_t)(brow + 16 + r) * K2_ + kg * 8);
  const short8* Bp0 = (const short8*)(Bt + (size_t)(bcol + r) * K2_ + kg * 8);
  const short8* Bp1 = (const short8*)(Bt + (size_t)(bcol + 16 + r) * K2_ + kg * 8);
  f32x4 acc[2][2];
  acc[0][0] = (f32x4){0,0,0,0}; acc[0][1] = acc[0][0];
  acc[1][0] = acc[0][0];        acc[1][1] = acc[0][0];
  #pragma unroll 4
  for (int k = 0; k < K2_ / 32; ++k) {
    short8 a0 = Ap0[4 * k], a1 = Ap1[4 * k];
    short8 b0 = Bp0[4 * k], b1 = Bp1[4 * k];
    acc[0][0] = __builtin_amdgcn_mfma_f32_16x16x32_bf16(a0, b0, acc[0][0], 0, 0, 0);
    acc[0][1] = __builtin_amdgcn_mfma_f32_16x16x32_bf16(a0, b1, acc[0][1], 0, 0, 0);
    acc[1][0] = __builtin_amdgcn_mfma_f32_16x16x32_bf16(a1, b0, acc[1][0], 0, 0, 0);
    acc[1][1] = __builtin_amdgcn_mfma_f32_16x16x32_bf16(a1, b1, acc[1][1], 0, 0, 0);
  }
  #pragma unroll
  for (int mi = 0; mi < 2; ++mi)
    #pragma unroll
    for (int ni = 0; ni < 2; ++ni) {
      int col = bcol + ni * 16 + r;
      float b8[A_];
      #pragma unroll
      for (int a = 0; a < A_; ++a) b8[a] = fc2_b[a * C_ + col];
      #pragma unroll
      for (int reg = 0; reg < 4; ++reg) {
        int row = brow + mi * 16 + kg * 4 + reg;
        const float* g = gate + (size_t)row * A_;
        float bias = 0.f;
        #pragma unroll
        for (int a = 0; a < A_; ++a) bias += g[a] * b8[a];
        float mixed = acc[mi][ni][reg] + bias;
        s_out[(size_t)row * C_ + col] = 1.0f + 1.0f / (1.0f + __expf(-mixed));
      }
    }
}

// ---------------- 6. out = features * (1 + sigmoid(mixed)) ----------------
__global__ void apply_k(const float4* __restrict__ f, const float* __restrict__ s,
                        float4* __restrict__ out, unsigned total4) {
  unsigned i = blockIdx.x * blockDim.x + threadIdx.x;
  unsigned stride = gridDim.x * blockDim.x;
  for (; i < total4; i += stride) {
    float4 v = f[i];
    float m = s[i / 49u];          // 49 float4 per (b,c) row
    v.x *= m; v.y *= m; v.z *= m; v.w *= m;
    out[i] = v;
  }
}

extern "C" void kernel_launch(void* const* d_in, const int* in_sizes, int n_in,
                              void* d_out, int out_size, void* d_ws, size_t ws_size,
                              hipStream_t stream) {
  const float* features = (const float*)d_in[0];
  const float* fc_w  = (const float*)d_in[1];
  const float* fc_b  = (const float*)d_in[2];
  const float* fc1_w = (const float*)d_in[3];
  const float* fc1_b = (const float*)d_in[4];
  const float* fc2_w = (const float*)d_in[5];
  const float* fc2_b = (const float*)d_in[6];
  float* out = (float*)d_out;
  char* ws = (char*)d_ws;

  float*          pooled  = (float*)(ws);                       // 4 MB
  unsigned short* pooledb = (unsigned short*)(ws + 0x400000);   // 2 MB
  float*          gate    = (float*)(ws + 0x600000);            // 32 KB
  unsigned short* gh      = (unsigned short*)(ws + 0x610000);   // 4 MB
  unsigned short* w1t     = (unsigned short*)(ws + 0xA10000);   // 4 MB
  unsigned short* w2t     = (unsigned short*)(ws + 0xE10000);   // 4 MB
  float*          s_buf   = (float*)(ws + 0x1210000);           // 4 MB

  pool_k<<<B_ * C_ / 4, 256, 0, stream>>>(features, pooled, pooledb);
  gate_k<<<B_, 256, 0, stream>>>(pooled, fc_w, fc_b, gate);
  // fc1_w [A][C=1024][CH=256] -> w1t [A][CH][C] (n-major, k-contig)
  tconv_k<<<dim3(8, 32, 8), 256, 0, stream>>>(fc1_w, w1t, 256, C_ * CH_, CH_ * C_, C_);
  // fc2_w [A][CH=256][C=1024] -> w2t [C][A*CH] (c rows, k=(a,ch) contiguous): col offset a*256
  tconv_k<<<dim3(32, 8, 8), 256, 0, stream>>>(fc2_w, w2t, 1024, CH_ * C_, CH_, K2_);
  gemm1_k<<<dim3(16, 32), 256, 0, stream>>>(pooledb, w1t, fc1_b, gate, gh);
  gemm2_k<<<dim3(16, 16), 256, 0, stream>>>(gh, w2t, gate, fc2_b, s_buf);
  apply_k<<<8192, 256, 0, stream>>>((const float4*)features, s_buf, (float4*)out,
                                    (unsigned)(out_size / 4));
}

// Round 3
// 555.573 us; speedup vs baseline: 1.1856x; 1.1856x over previous
//
#include <hip/hip_runtime.h>

#define B_  1024
#define C_  1024
#define HW_ 196
#define A_  8
#define CH_ 256
#define N1_ 2048   // A*CH
#define K2_ 2048   // A*CH

typedef __attribute__((ext_vector_type(8))) short short8;
typedef __attribute__((ext_vector_type(4))) float f32x4;

static __device__ __forceinline__ unsigned short f2bf(float x) {
  union { float f; unsigned u; } v; v.f = x;
  unsigned r = (v.u + 0x7FFFu + ((v.u >> 16) & 1u)) >> 16;  // RNE
  return (unsigned short)r;
}

// ---------------- 1. global average pool ----------------
// Grid-stride waves; each wave does 64 rows, one float4 load per row (49 lanes).
__global__ __launch_bounds__(256) void pool_k(const float* __restrict__ f,
                                              float* __restrict__ pooled,
                                              unsigned short* __restrict__ pooledb) {
  int wid = (blockIdx.x * 256 + threadIdx.x) >> 6;   // global wave id, 0..16383
  int lane = threadIdx.x & 63;
  unsigned row0 = (unsigned)wid * 64;
  const f32x4* base = (const f32x4*)f;
  #pragma unroll 2
  for (int it = 0; it < 64; ++it) {
    unsigned row = row0 + it;
    float s = 0.f;
    if (lane < 49) {
      f32x4 v = __builtin_nontemporal_load(&base[(size_t)row * 49 + lane]);
      s = v.x + v.y + v.z + v.w;
    }
    #pragma unroll
    for (int off = 32; off > 0; off >>= 1) s += __shfl_down(s, off, 64);
    if (lane == 0) {
      float m = s * (1.0f / 196.0f);
      pooled[row] = m;
      pooledb[row] = f2bf(m);
    }
  }
}

// ---------------- 2. softmax gate over experts: one block per b ----------------
__global__ void gate_k(const float* __restrict__ pooled, const float* __restrict__ fc_w,
                       const float* __restrict__ fc_b, float* __restrict__ gate) {
  __shared__ float dots[A_];
  int b = blockIdx.x;
  int wave = threadIdx.x >> 6, lane = threadIdx.x & 63;
  const float* p = pooled + (size_t)b * C_;
  for (int e = wave; e < A_; e += 4) {
    const float* wrow = fc_w + (size_t)e * C_;
    float sum = 0.f;
    for (int c = lane; c < C_; c += 64) sum += p[c] * wrow[c];
    #pragma unroll
    for (int off = 32; off > 0; off >>= 1) sum += __shfl_down(sum, off, 64);
    if (lane == 0) dots[e] = sum + fc_b[e];
  }
  __syncthreads();
  if (threadIdx.x == 0) {
    float mx = dots[0];
    for (int e = 1; e < A_; ++e) mx = fmaxf(mx, dots[e]);
    float ex[A_], se = 0.f;
    for (int e = 0; e < A_; ++e) { ex[e] = __expf(dots[e] - mx); se += ex[e]; }
    float inv = 1.0f / se;
    for (int e = 0; e < A_; ++e) gate[(size_t)b * A_ + e] = ex[e] * inv;
  }
}

// ------- 3. both weight transposes (fp32 -> bf16, [r][c] -> [c][r]) in ONE launch -------
// tiles 0..2047:  fc1_w [A][C][CH] -> w1t [A][CH][C]     (Cc=CH, OS=C)
// tiles 2048..4095: fc2_w [A][CH][C] -> w2t [C][A*CH]    (Cc=C,  OS=K2, col base z*CH)
__global__ void tconv_k(const float* __restrict__ fc1_w, const float* __restrict__ fc2_w,
                        unsigned short* __restrict__ w1t, unsigned short* __restrict__ w2t) {
  __shared__ float tile[32][33];
  int t = blockIdx.x;
  const float* in; unsigned short* out; int Cc, OS, c0, r0;
  if (t < 2048) {
    int z = t >> 8, rem = t & 255;
    in  = fc1_w + (size_t)z * (C_ * CH_);
    out = w1t   + (size_t)z * (CH_ * C_);
    Cc = CH_; OS = C_;
    c0 = (rem & 7) * 32;  r0 = (rem >> 3) * 32;
  } else {
    t -= 2048;
    int z = t >> 8, rem = t & 255;
    in  = fc2_w + (size_t)z * (CH_ * C_);
    out = w2t   + (size_t)z * CH_;
    Cc = C_; OS = K2_;
    c0 = (rem & 31) * 32; r0 = (rem >> 5) * 32;
  }
  int tx = threadIdx.x & 31, ty = threadIdx.x >> 5;   // 32x8 threads
  #pragma unroll
  for (int i = 0; i < 32; i += 8)
    tile[ty + i][tx] = in[(size_t)(r0 + ty + i) * Cc + c0 + tx];
  __syncthreads();
  #pragma unroll
  for (int i = 0; i < 32; i += 8)
    out[(size_t)(c0 + ty + i) * OS + r0 + tx] = f2bf(tile[tx][ty + i]);
}

// ---------------- 4. GEMM1: gh[b,n] = relu(pooled.fc1_w + b1) * gate ----------------
__global__ __launch_bounds__(256) void gemm1_k(const unsigned short* __restrict__ Ab,
                                               const unsigned short* __restrict__ Bt,
                                               const float* __restrict__ fc1_b,
                                               const float* __restrict__ gate,
                                               unsigned short* __restrict__ gh) {
  int w = threadIdx.x >> 6, lane = threadIdx.x & 63;
  int r = lane & 15, kg = lane >> 4;
  int brow = blockIdx.x * 64 + (w >> 1) * 32;
  int bcol = blockIdx.y * 64 + (w & 1) * 32;
  const short8* Ap0 = (const short8*)(Ab + (size_t)(brow + r) * C_ + kg * 8);
  const short8* Ap1 = (const short8*)(Ab + (size_t)(brow + 16 + r) * C_ + kg * 8);
  const short8* Bp0 = (const short8*)(Bt + (size_t)(bcol + r) * C_ + kg * 8);
  const short8* Bp1 = (const short8*)(Bt + (size_t)(bcol + 16 + r) * C_ + kg * 8);
  f32x4 acc[2][2];
  acc[0][0] = (f32x4){0,0,0,0}; acc[0][1] = acc[0][0];
  acc[1][0] = acc[0][0];        acc[1][1] = acc[0][0];
  #pragma unroll 4
  for (int k = 0; k < C_ / 32; ++k) {
    short8 a0 = Ap0[4 * k], a1 = Ap1[4 * k];
    short8 b0 = Bp0[4 * k], b1 = Bp1[4 * k];
    acc[0][0] = __builtin_amdgcn_mfma_f32_16x16x32_bf16(a0, b0, acc[0][0], 0, 0, 0);
    acc[0][1] = __builtin_amdgcn_mfma_f32_16x16x32_bf16(a0, b1, acc[0][1], 0, 0, 0);
    acc[1][0] = __builtin_amdgcn_mfma_f32_16x16x32_bf16(a1, b0, acc[1][0], 0, 0, 0);
    acc[1][1] = __builtin_amdgcn_mfma_f32_16x16x32_bf16(a1, b1, acc[1][1], 0, 0, 0);
  }
  #pragma unroll
  for (int mi = 0; mi < 2; ++mi)
    #pragma unroll
    for (int ni = 0; ni < 2; ++ni) {
      int col = bcol + ni * 16 + r;
      int aidx = col >> 8;
      float bias = fc1_b[col];
      #pragma unroll
      for (int reg = 0; reg < 4; ++reg) {
        int row = brow + mi * 16 + kg * 4 + reg;
        float val = acc[mi][ni][reg] + bias;
        val = fmaxf(val, 0.f) * gate[row * A_ + aidx];
        gh[(size_t)row * N1_ + col] = f2bf(val);
      }
    }
}

// ---------------- 5. GEMM2: mixed = gh.fc2_w + gate.fc2_b ; s = 1+sigmoid ----------------
__global__ __launch_bounds__(256) void gemm2_k(const unsigned short* __restrict__ Ab,
                                               const unsigned short* __restrict__ Bt,
                                               const float* __restrict__ gate,
                                               const float* __restrict__ fc2_b,
                                               float* __restrict__ s_out) {
  int w = threadIdx.x >> 6, lane = threadIdx.x & 63;
  int r = lane & 15, kg = lane >> 4;
  int brow = blockIdx.x * 64 + (w >> 1) * 32;
  int bcol = blockIdx.y * 64 + (w & 1) * 32;
  const short8* Ap0 = (const short8*)(Ab + (size_t)(brow + r) * K2_ + kg * 8);
  const short8* Ap1 = (const short8*)(Ab + (size_t)(brow + 16 + r) * K2_ + kg * 8);
  const short8* Bp0 = (const short8*)(Bt + (size_t)(bcol + r) * K2_ + kg * 8);
  const short8* Bp1 = (const short8*)(Bt + (size_t)(bcol + 16 + r) * K2_ + kg * 8);
  f32x4 acc[2][2];
  acc[0][0] = (f32x4){0,0,0,0}; acc[0][1] = acc[0][0];
  acc[1][0] = acc[0][0];        acc[1][1] = acc[0][0];
  #pragma unroll 4
  for (int k = 0; k < K2_ / 32; ++k) {
    short8 a0 = Ap0[4 * k], a1 = Ap1[4 * k];
    short8 b0 = Bp0[4 * k], b1 = Bp1[4 * k];
    acc[0][0] = __builtin_amdgcn_mfma_f32_16x16x32_bf16(a0, b0, acc[0][0], 0, 0, 0);
    acc[0][1] = __builtin_amdgcn_mfma_f32_16x16x32_bf16(a0, b1, acc[0][1], 0, 0, 0);
    acc[1][0] = __builtin_amdgcn_mfma_f32_16x16x32_bf16(a1, b0, acc[1][0], 0, 0, 0);
    acc[1][1] = __builtin_amdgcn_mfma_f32_16x16x32_bf16(a1, b1, acc[1][1], 0, 0, 0);
  }
  #pragma unroll
  for (int mi = 0; mi < 2; ++mi)
    #pragma unroll
    for (int ni = 0; ni < 2; ++ni) {
      int col = bcol + ni * 16 + r;
      float b8[A_];
      #pragma unroll
      for (int a = 0; a < A_; ++a) b8[a] = fc2_b[a * C_ + col];
      #pragma unroll
      for (int reg = 0; reg < 4; ++reg) {
        int row = brow + mi * 16 + kg * 4 + reg;
        const float* g = gate + (size_t)row * A_;
        float bias = 0.f;
        #pragma unroll
        for (int a = 0; a < A_; ++a) bias += g[a] * b8[a];
        float mixed = acc[mi][ni][reg] + bias;
        s_out[(size_t)row * C_ + col] = 1.0f + 1.0f / (1.0f + __expf(-mixed));
      }
    }
}

// ---------------- 6. out = features * s[row] ----------------
__global__ __launch_bounds__(256) void apply_k(const f32x4* __restrict__ f,
                                               const float* __restrict__ s,
                                               f32x4* __restrict__ out, unsigned total4) {
  unsigned i = blockIdx.x * 256 + threadIdx.x;
  unsigned stride = gridDim.x * 256;
  for (; i < total4; i += stride) {
    f32x4 v = __builtin_nontemporal_load(&f[i]);
    float m = s[i / 49u];          // 49 float4 per (b,c) row
    v *= m;
    __builtin_nontemporal_store(v, &out[i]);
  }
}

extern "C" void kernel_launch(void* const* d_in, const int* in_sizes, int n_in,
                              void* d_out, int out_size, void* d_ws, size_t ws_size,
                              hipStream_t stream) {
  const float* features = (const float*)d_in[0];
  const float* fc_w  = (const float*)d_in[1];
  const float* fc_b  = (const float*)d_in[2];
  const float* fc1_w = (const float*)d_in[3];
  const float* fc1_b = (const float*)d_in[4];
  const float* fc2_w = (const float*)d_in[5];
  const float* fc2_b = (const float*)d_in[6];
  float* out = (float*)d_out;
  char* ws = (char*)d_ws;

  float*          pooled  = (float*)(ws);                       // 4 MB
  unsigned short* pooledb = (unsigned short*)(ws + 0x400000);   // 2 MB
  float*          gate    = (float*)(ws + 0x600000);            // 32 KB
  unsigned short* gh      = (unsigned short*)(ws + 0x610000);   // 4 MB
  unsigned short* w1t     = (unsigned short*)(ws + 0xA10000);   // 4 MB
  unsigned short* w2t     = (unsigned short*)(ws + 0xE10000);   // 4 MB
  float*          s_buf   = (float*)(ws + 0x1210000);           // 4 MB

  pool_k<<<4096, 256, 0, stream>>>(features, pooled, pooledb);
  gate_k<<<B_, 256, 0, stream>>>(pooled, fc_w, fc_b, gate);
  tconv_k<<<4096, 256, 0, stream>>>(fc1_w, fc2_w, w1t, w2t);
  gemm1_k<<<dim3(16, 32), 256, 0, stream>>>(pooledb, w1t, fc1_b, gate, gh);
  gemm2_k<<<dim3(16, 16), 256, 0, stream>>>(gh, w2t, gate, fc2_b, s_buf);
  apply_k<<<8192, 256, 0, stream>>>((const f32x4*)features, s_buf, (f32x4*)out,
                                    (unsigned)(out_size / 4));
}

// Round 4
// 553.156 us; speedup vs baseline: 1.1908x; 1.0044x over previous
//
#include <hip/hip_runtime.h>

#define B_  1024
#define C_  1024
#define HW_ 196
#define A_  8
#define CH_ 256
#define N1_ 2048   // A*CH
#define K2_ 2048   // A*CH

typedef __attribute__((ext_vector_type(8))) short short8;
typedef __attribute__((ext_vector_type(4))) float f32x4;
typedef __attribute__((ext_vector_type(4))) unsigned short us4;

static __device__ __forceinline__ unsigned short f2bf(float x) {
  union { float f; unsigned u; } v; v.f = x;
  unsigned r = (v.u + 0x7FFFu + ((v.u >> 16) & 1u)) >> 16;  // RNE
  return (unsigned short)r;
}

// ---- 1. pool (blocks 0..4095) + both weight transposes (blocks 4096..8191) ----
// pool: each wave does 64 rows; per 4 rows: 4 independent f32x4 loads (branch-free,
// clamped addr), 4 interleaved shuffle-reduce chains, vectorized stores.
// tconv: fp32->bf16 32x32 LDS transpose, two weight tensors by tile range.
__global__ __launch_bounds__(256) void pooltc_k(const float* __restrict__ f,
                                                float* __restrict__ pooled,
                                                unsigned short* __restrict__ pooledb,
                                                const float* __restrict__ fc1_w,
                                                const float* __restrict__ fc2_w,
                                                unsigned short* __restrict__ w1t,
                                                unsigned short* __restrict__ w2t) {
  __shared__ float tile[32][33];
  if (blockIdx.x < 4096) {
    int wid = (blockIdx.x * 256 + threadIdx.x) >> 6;   // 0..16383
    int lane = threadIdx.x & 63;
    int lc = lane < 49 ? lane : 48;                     // clamped: lanes 49..63 re-read lane48's line
    float msk = lane < 49 ? 1.0f : 0.0f;
    unsigned row0 = (unsigned)wid * 64;
    const f32x4* base = (const f32x4*)f;
    for (int it = 0; it < 64; it += 4) {
      unsigned row = row0 + it;
      f32x4 v0 = base[(size_t)(row + 0) * 49 + lc];
      f32x4 v1 = base[(size_t)(row + 1) * 49 + lc];
      f32x4 v2 = base[(size_t)(row + 2) * 49 + lc];
      f32x4 v3 = base[(size_t)(row + 3) * 49 + lc];
      float s0 = (v0.x + v0.y + v0.z + v0.w) * msk;
      float s1 = (v1.x + v1.y + v1.z + v1.w) * msk;
      float s2 = (v2.x + v2.y + v2.z + v2.w) * msk;
      float s3 = (v3.x + v3.y + v3.z + v3.w) * msk;
      #pragma unroll
      for (int off = 32; off > 0; off >>= 1) {
        s0 += __shfl_xor(s0, off, 64);
        s1 += __shfl_xor(s1, off, 64);
        s2 += __shfl_xor(s2, off, 64);
        s3 += __shfl_xor(s3, off, 64);
      }
      if (lane == 0) {
        f32x4 m = {s0, s1, s2, s3};
        m *= (1.0f / 196.0f);
        *(f32x4*)&pooled[row] = m;
        us4 mb = {f2bf(m.x), f2bf(m.y), f2bf(m.z), f2bf(m.w)};
        *(us4*)&pooledb[row] = mb;
      }
    }
  } else {
    int t = blockIdx.x - 4096;
    const float* in; unsigned short* out; int Cc, OS, c0, r0;
    if (t < 2048) {             // fc1_w [A][C][CH] -> w1t [A][CH][C]
      int z = t >> 8, rem = t & 255;
      in  = fc1_w + (size_t)z * (C_ * CH_);
      out = w1t   + (size_t)z * (CH_ * C_);
      Cc = CH_; OS = C_;
      c0 = (rem & 7) * 32;  r0 = (rem >> 3) * 32;
    } else {                    // fc2_w [A][CH][C] -> w2t [C][A*CH]
      t -= 2048;
      int z = t >> 8, rem = t & 255;
      in  = fc2_w + (size_t)z * (CH_ * C_);
      out = w2t   + (size_t)z * CH_;
      Cc = C_; OS = K2_;
      c0 = (rem & 31) * 32; r0 = (rem >> 5) * 32;
    }
    int tx = threadIdx.x & 31, ty = threadIdx.x >> 5;   // 32x8 threads
    #pragma unroll
    for (int i = 0; i < 32; i += 8)
      tile[ty + i][tx] = in[(size_t)(r0 + ty + i) * Cc + c0 + tx];
    __syncthreads();
    #pragma unroll
    for (int i = 0; i < 32; i += 8)
      out[(size_t)(c0 + ty + i) * OS + r0 + tx] = f2bf(tile[tx][ty + i]);
  }
}

// ---------------- 2. softmax gate over experts: one block per b ----------------
__global__ void gate_k(const float* __restrict__ pooled, const float* __restrict__ fc_w,
                       const float* __restrict__ fc_b, float* __restrict__ gate) {
  __shared__ float dots[A_];
  int b = blockIdx.x;
  int wave = threadIdx.x >> 6, lane = threadIdx.x & 63;
  const float* p = pooled + (size_t)b * C_;
  for (int e = wave; e < A_; e += 4) {
    const float* wrow = fc_w + (size_t)e * C_;
    float sum = 0.f;
    for (int c = lane; c < C_; c += 64) sum += p[c] * wrow[c];
    #pragma unroll
    for (int off = 32; off > 0; off >>= 1) sum += __shfl_down(sum, off, 64);
    if (lane == 0) dots[e] = sum + fc_b[e];
  }
  __syncthreads();
  if (threadIdx.x == 0) {
    float mx = dots[0];
    for (int e = 1; e < A_; ++e) mx = fmaxf(mx, dots[e]);
    float ex[A_], se = 0.f;
    for (int e = 0; e < A_; ++e) { ex[e] = __expf(dots[e] - mx); se += ex[e]; }
    float inv = 1.0f / se;
    for (int e = 0; e < A_; ++e) gate[(size_t)b * A_ + e] = ex[e] * inv;
  }
}

// ---------------- 3. GEMM1: gh[b,n] = relu(pooled.fc1_w + b1) * gate ----------------
__global__ __launch_bounds__(256) void gemm1_k(const unsigned short* __restrict__ Ab,
                                               const unsigned short* __restrict__ Bt,
                                               const float* __restrict__ fc1_b,
                                               const float* __restrict__ gate,
                                               unsigned short* __restrict__ gh) {
  int w = threadIdx.x >> 6, lane = threadIdx.x & 63;
  int r = lane & 15, kg = lane >> 4;
  int brow = blockIdx.x * 64 + (w >> 1) * 32;
  int bcol = blockIdx.y * 64 + (w & 1) * 32;
  const short8* Ap0 = (const short8*)(Ab + (size_t)(brow + r) * C_ + kg * 8);
  const short8* Ap1 = (const short8*)(Ab + (size_t)(brow + 16 + r) * C_ + kg * 8);
  const short8* Bp0 = (const short8*)(Bt + (size_t)(bcol + r) * C_ + kg * 8);
  const short8* Bp1 = (const short8*)(Bt + (size_t)(bcol + 16 + r) * C_ + kg * 8);
  f32x4 acc[2][2];
  acc[0][0] = (f32x4){0,0,0,0}; acc[0][1] = acc[0][0];
  acc[1][0] = acc[0][0];        acc[1][1] = acc[0][0];
  #pragma unroll 4
  for (int k = 0; k < C_ / 32; ++k) {
    short8 a0 = Ap0[4 * k], a1 = Ap1[4 * k];
    short8 b0 = Bp0[4 * k], b1 = Bp1[4 * k];
    acc[0][0] = __builtin_amdgcn_mfma_f32_16x16x32_bf16(a0, b0, acc[0][0], 0, 0, 0);
    acc[0][1] = __builtin_amdgcn_mfma_f32_16x16x32_bf16(a0, b1, acc[0][1], 0, 0, 0);
    acc[1][0] = __builtin_amdgcn_mfma_f32_16x16x32_bf16(a1, b0, acc[1][0], 0, 0, 0);
    acc[1][1] = __builtin_amdgcn_mfma_f32_16x16x32_bf16(a1, b1, acc[1][1], 0, 0, 0);
  }
  #pragma unroll
  for (int mi = 0; mi < 2; ++mi)
    #pragma unroll
    for (int ni = 0; ni < 2; ++ni) {
      int col = bcol + ni * 16 + r;
      int aidx = col >> 8;
      float bias = fc1_b[col];
      #pragma unroll
      for (int reg = 0; reg < 4; ++reg) {
        int row = brow + mi * 16 + kg * 4 + reg;
        float val = acc[mi][ni][reg] + bias;
        val = fmaxf(val, 0.f) * gate[row * A_ + aidx];
        gh[(size_t)row * N1_ + col] = f2bf(val);
      }
    }
}

// ---------------- 4. GEMM2: mixed = gh.fc2_w + gate.fc2_b ; s = 1+sigmoid ----------------
__global__ __launch_bounds__(256) void gemm2_k(const unsigned short* __restrict__ Ab,
                                               const unsigned short* __restrict__ Bt,
                                               const float* __restrict__ gate,
                                               const float* __restrict__ fc2_b,
                                               float* __restrict__ s_out) {
  int w = threadIdx.x >> 6, lane = threadIdx.x & 63;
  int r = lane & 15, kg = lane >> 4;
  int brow = blockIdx.x * 64 + (w >> 1) * 32;
  int bcol = blockIdx.y * 64 + (w & 1) * 32;
  const short8* Ap0 = (const short8*)(Ab + (size_t)(brow + r) * K2_ + kg * 8);
  const short8* Ap1 = (const short8*)(Ab + (size_t)(brow + 16 + r) * K2_ + kg * 8);
  const short8* Bp0 = (const short8*)(Bt + (size_t)(bcol + r) * K2_ + kg * 8);
  const short8* Bp1 = (const short8*)(Bt + (size_t)(bcol + 16 + r) * K2_ + kg * 8);
  f32x4 acc[2][2];
  acc[0][0] = (f32x4){0,0,0,0}; acc[0][1] = acc[0][0];
  acc[1][0] = acc[0][0];        acc[1][1] = acc[0][0];
  #pragma unroll 4
  for (int k = 0; k < K2_ / 32; ++k) {
    short8 a0 = Ap0[4 * k], a1 = Ap1[4 * k];
    short8 b0 = Bp0[4 * k], b1 = Bp1[4 * k];
    acc[0][0] = __builtin_amdgcn_mfma_f32_16x16x32_bf16(a0, b0, acc[0][0], 0, 0, 0);
    acc[0][1] = __builtin_amdgcn_mfma_f32_16x16x32_bf16(a0, b1, acc[0][1], 0, 0, 0);
    acc[1][0] = __builtin_amdgcn_mfma_f32_16x16x32_bf16(a1, b0, acc[1][0], 0, 0, 0);
    acc[1][1] = __builtin_amdgcn_mfma_f32_16x16x32_bf16(a1, b1, acc[1][1], 0, 0, 0);
  }
  #pragma unroll
  for (int mi = 0; mi < 2; ++mi)
    #pragma unroll
    for (int ni = 0; ni < 2; ++ni) {
      int col = bcol + ni * 16 + r;
      float b8[A_];
      #pragma unroll
      for (int a = 0; a < A_; ++a) b8[a] = fc2_b[a * C_ + col];
      #pragma unroll
      for (int reg = 0; reg < 4; ++reg) {
        int row = brow + mi * 16 + kg * 4 + reg;
        const float* g = gate + (size_t)row * A_;
        float bias = 0.f;
        #pragma unroll
        for (int a = 0; a < A_; ++a) bias += g[a] * b8[a];
        float mixed = acc[mi][ni][reg] + bias;
        s_out[(size_t)row * C_ + col] = 1.0f + 1.0f / (1.0f + __expf(-mixed));
      }
    }
}

// ---------------- 5. out = features * s[row] ----------------
__global__ __launch_bounds__(256) void apply_k(const f32x4* __restrict__ f,
                                               const float* __restrict__ s,
                                               f32x4* __restrict__ out, unsigned total4) {
  unsigned i = blockIdx.x * 256 + threadIdx.x;
  unsigned stride = gridDim.x * 256;
  for (; i < total4; i += stride) {
    f32x4 v = __builtin_nontemporal_load(&f[i]);
    float m = s[i / 49u];          // 49 float4 per (b,c) row
    v *= m;
    __builtin_nontemporal_store(v, &out[i]);
  }
}

extern "C" void kernel_launch(void* const* d_in, const int* in_sizes, int n_in,
                              void* d_out, int out_size, void* d_ws, size_t ws_size,
                              hipStream_t stream) {
  const float* features = (const float*)d_in[0];
  const float* fc_w  = (const float*)d_in[1];
  const float* fc_b  = (const float*)d_in[2];
  const float* fc1_w = (const float*)d_in[3];
  const float* fc1_b = (const float*)d_in[4];
  const float* fc2_w = (const float*)d_in[5];
  const float* fc2_b = (const float*)d_in[6];
  float* out = (float*)d_out;
  char* ws = (char*)d_ws;

  float*          pooled  = (float*)(ws);                       // 4 MB
  unsigned short* pooledb = (unsigned short*)(ws + 0x400000);   // 2 MB
  float*          gate    = (float*)(ws + 0x600000);            // 32 KB
  unsigned short* gh      = (unsigned short*)(ws + 0x610000);   // 4 MB
  unsigned short* w1t     = (unsigned short*)(ws + 0xA10000);   // 4 MB
  unsigned short* w2t     = (unsigned short*)(ws + 0xE10000);   // 4 MB
  float*          s_buf   = (float*)(ws + 0x1210000);           // 4 MB

  pooltc_k<<<8192, 256, 0, stream>>>(features, pooled, pooledb, fc1_w, fc2_w, w1t, w2t);
  gate_k<<<B_, 256, 0, stream>>>(pooled, fc_w, fc_b, gate);
  gemm1_k<<<dim3(16, 32), 256, 0, stream>>>(pooledb, w1t, fc1_b, gate, gh);
  gemm2_k<<<dim3(16, 16), 256, 0, stream>>>(gh, w2t, gate, fc2_b, s_buf);
  apply_k<<<8192, 256, 0, stream>>>((const f32x4*)features, s_buf, (f32x4*)out,
                                    (unsigned)(out_size / 4));
}